// Round 1
// baseline (34.092 us; speedup 1.0000x reference)
//
#include <hip/hip_runtime.h>

#define B 32
#define L 512
#define D 768
#define M 24
#define P (M * (M - 1))   // 552

// K1: pooled[b][m][d] = mean_{l in [s,e)} seq[b, head[b,l], d]
__global__ void pool_kernel(const float* __restrict__ seq,   // B,L,D
                            const int*   __restrict__ head,  // B,L
                            const int*   __restrict__ em,    // B,M,2
                            float*       __restrict__ pooled)// B,M,D
{
    int bm = blockIdx.x;
    int b = bm / M, m = bm - b * M;
    int s = em[(b * M + m) * 2 + 0];
    int e = em[(b * M + m) * 2 + 1];
    float inv = 1.0f / (float)(e - s);
    const float* seqb  = seq  + (size_t)b * L * D;
    const int*   headb = head + b * L;
    int d0 = threadIdx.x;                 // 256 threads, 3 elems each (768)
    float a0 = 0.f, a1 = 0.f, a2 = 0.f;
    for (int l = s; l < e; ++l) {
        const float* row = seqb + (size_t)headb[l] * D;
        a0 += row[d0];
        a1 += row[d0 + 256];
        a2 += row[d0 + 512];
    }
    float* o = pooled + (size_t)(b * M + m) * D;
    o[d0]       = a0 * inv;
    o[d0 + 256] = a1 * inv;
    o[d0 + 512] = a2 * inv;
}

// K2: one thread per float4 of relation_predictions (B*P rows x 1536 f32 = 384 quads/row)
__global__ void rel_kernel(const float* __restrict__ pooled,
                           float*       __restrict__ out)
{
    long idx = (long)blockIdx.x * blockDim.x + threadIdx.x;   // quad index
    int row = (int)(idx / 384);
    int q   = (int)(idx - (long)row * 384);
    int b = row / P;
    int p = row - b * P;
    int i = p / (M - 1);
    int r = p - i * (M - 1);
    int j = (r < i) ? r : r + 1;
    int src_m = (q < 192) ? i : j;
    int qq    = (q < 192) ? q : q - 192;
    const float4* srcrow = (const float4*)(pooled + (size_t)(b * M + src_m) * D);
    float4 v = srcrow[qq];
    ((float4*)out)[idx] = v;
}

// K3: pairs as float32 values: [b, s_i, e_i, s_j, e_j] per (b,p) row
__global__ void pairs_kernel(const int* __restrict__ em,
                             float*     __restrict__ out)     // B*P*5
{
    int idx = blockIdx.x * blockDim.x + threadIdx.x;
    if (idx >= B * P) return;
    int b = idx / P;
    int p = idx - b * P;
    int i = p / (M - 1);
    int r = p - i * (M - 1);
    int j = (r < i) ? r : r + 1;
    const int* emb = em + b * M * 2;
    float* o = out + (size_t)idx * 5;
    o[0] = (float)b;
    o[1] = (float)emb[2 * i];
    o[2] = (float)emb[2 * i + 1];
    o[3] = (float)emb[2 * j];
    o[4] = (float)emb[2 * j + 1];
}

extern "C" void kernel_launch(void* const* d_in, const int* in_sizes, int n_in,
                              void* d_out, int out_size, void* d_ws, size_t ws_size,
                              hipStream_t stream) {
    const float* seq  = (const float*)d_in[0];
    const int*   head = (const int*)d_in[1];
    const int*   em   = (const int*)d_in[2];
    float* out    = (float*)d_out;
    float* pooled = (float*)d_ws;                 // B*M*D f32 = 2.36 MB

    pool_kernel<<<B * M, 256, 0, stream>>>(seq, head, em, pooled);

    long quads = (long)B * P * 384;               // 6,782,976 (divisible by 256)
    rel_kernel<<<(int)(quads / 256), 256, 0, stream>>>(pooled, out);

    pairs_kernel<<<(B * P + 255) / 256, 256, 0, stream>>>(
        em, out + (size_t)B * P * 2 * D);
}

// Round 2
// 27.989 us; speedup vs baseline: 1.2181x; 1.2181x over previous
//
#include <hip/hip_runtime.h>

#define B 32
#define L 512
#define D 768
#define M 24
#define P (M * (M - 1))   // 552
#define Q4 (D / 4)        // 192 float4 per half-row

// One block per (b, m, half). 192 threads, one float4 of the pooled vector each.
// half==0: this mention is the OBJ (i) of rows p = m*23 + r, writes first 768 floats.
// half==1: this mention is the SUB (j) of rows p = i*23 + r(i), writes last 768 floats.
// Obj blocks additionally write the 5-int pair rows (as f32 values).
__global__ void fused_kernel(const float* __restrict__ seq,   // B,L,D
                             const int*   __restrict__ head,  // B,L
                             const int*   __restrict__ em,    // B,M,2
                             float*       __restrict__ out)   // B*P*1536 rel | B*P*5 pairs
{
    int blk  = blockIdx.x;         // 0 .. B*M*2-1
    int half = blk & 1;
    int bm   = blk >> 1;           // obj/sub blocks for same mention adjacent -> L2 reuse
    int b = bm / M, m = bm - b * M;
    int t = threadIdx.x;           // 0..191

    int s = em[bm * 2 + 0];
    int e = em[bm * 2 + 1];
    float inv = 1.0f / (float)(e - s);

    const float* seqb  = seq  + (size_t)b * L * D;
    const int*   headb = head + b * L;

    float4 acc = make_float4(0.f, 0.f, 0.f, 0.f);
    for (int l = s; l < e; ++l) {
        const float4* row = (const float4*)(seqb + (size_t)headb[l] * D);
        float4 v = row[t];
        acc.x += v.x; acc.y += v.y; acc.z += v.z; acc.w += v.w;
    }
    acc.x *= inv; acc.y *= inv; acc.z *= inv; acc.w *= inv;

    float4* outq = (float4*)out;             // rel rows: 384 float4 each
    size_t rowbase = (size_t)b * P;

    if (half == 0) {
        // rows m*23 + r, obj half (quad offset t)
        size_t q = (rowbase + (size_t)m * 23) * 384 + t;
        #pragma unroll
        for (int r = 0; r < 23; ++r) {
            outq[q] = acc;
            q += 384;
        }
        // pairs: threads 0..22 write row (b, m*23+r)
        if (t < 23) {
            int r = t;
            int j = (r < m) ? r : r + 1;
            float* o = out + (size_t)B * P * 2 * D
                     + (size_t)(rowbase + (size_t)m * 23 + r) * 5;
            o[0] = (float)b;
            o[1] = (float)s;
            o[2] = (float)e;
            o[3] = (float)em[(b * M + j) * 2 + 0];
            o[4] = (float)em[(b * M + j) * 2 + 1];
        }
    } else {
        // this mention is j == m: for each i != m, r = (m<i) ? m : m-1
        #pragma unroll
        for (int i = 0; i < M; ++i) {
            if (i == m) continue;
            int r = (m < i) ? m : m - 1;
            size_t row = rowbase + (size_t)i * 23 + r;
            outq[row * 384 + 192 + t] = acc;
        }
    }
}

extern "C" void kernel_launch(void* const* d_in, const int* in_sizes, int n_in,
                              void* d_out, int out_size, void* d_ws, size_t ws_size,
                              hipStream_t stream) {
    const float* seq  = (const float*)d_in[0];
    const int*   head = (const int*)d_in[1];
    const int*   em   = (const int*)d_in[2];
    float* out = (float*)d_out;

    fused_kernel<<<B * M * 2, Q4, 0, stream>>>(seq, head, em, out);
}

// Round 4
// 27.275 us; speedup vs baseline: 1.2500x; 1.0262x over previous
//
#include <hip/hip_runtime.h>

#define B 32
#define L 512
#define D 768
#define M 24
#define P (M * (M - 1))   // 552
#define Q4 (D / 4)        // 192 float4 per half-row

typedef float f32x4 __attribute__((ext_vector_type(4)));

// One block per (b, m): 384 threads.
//  - threads 0..191 gather-average the mention's pooled vector (one float4 each),
//    store it to LDS.
//  - after sync: threads 0..191 write the OBJ half of 23 rows (p = m*23 + r),
//    threads 192..383 write the SUB half of 23 rows (p = i*23 + r(i), i != m).
//  - threads 0..22 also emit the pair rows (as f32 values).
__global__ void fused_kernel(const float* __restrict__ seq,   // B,L,D
                             const int*   __restrict__ head,  // B,L
                             const int*   __restrict__ em,    // B,M,2
                             float*       __restrict__ out)   // B*P*1536 rel | B*P*5 pairs
{
    __shared__ f32x4 pool[Q4];    // 3 KB

    int bm = blockIdx.x;           // 0 .. B*M-1
    int b = bm / M, m = bm - b * M;
    int t = threadIdx.x;           // 0..383

    int s = em[bm * 2 + 0];
    int e = em[bm * 2 + 1];

    if (t < Q4) {
        float inv = 1.0f / (float)(e - s);
        const float* seqb  = seq  + (size_t)b * L * D;
        const int*   headb = head + b * L;
        f32x4 acc = (f32x4)(0.f);
        for (int l = s; l < e; ++l) {
            const f32x4* row = (const f32x4*)(seqb + (size_t)headb[l] * D);
            acc += row[t];
        }
        acc *= inv;
        pool[t] = acc;
    }
    __syncthreads();

    f32x4* outq = (f32x4*)out;             // rel rows: 384 float4 each
    size_t rowbase = (size_t)b * P;

    if (t < Q4) {
        // OBJ half: rows m*23 + r, quad offset t
        f32x4 v = pool[t];
        size_t q = (rowbase + (size_t)m * 23) * 384 + t;
        #pragma unroll
        for (int r = 0; r < 23; ++r) {
            __builtin_nontemporal_store(v, &outq[q]);
            q += 384;
        }
        if (t < 23) {
            int r = t;
            int j = (r < m) ? r : r + 1;
            float* o = out + (size_t)B * P * 2 * D
                     + (size_t)(rowbase + (size_t)m * 23 + r) * 5;
            o[0] = (float)b;
            o[1] = (float)s;
            o[2] = (float)e;
            o[3] = (float)em[(b * M + j) * 2 + 0];
            o[4] = (float)em[(b * M + j) * 2 + 1];
        }
    } else {
        // SUB half: this mention is j == m; for each i != m, r = (m<i) ? m : m-1
        int tq = t - Q4;                      // 0..191
        f32x4 v = pool[tq];
        #pragma unroll
        for (int i = 0; i < M; ++i) {
            if (i == m) continue;
            int r = (m < i) ? m : m - 1;
            size_t row = rowbase + (size_t)i * 23 + r;
            __builtin_nontemporal_store(v, &outq[row * 384 + Q4 + tq]);
        }
    }
}

extern "C" void kernel_launch(void* const* d_in, const int* in_sizes, int n_in,
                              void* d_out, int out_size, void* d_ws, size_t ws_size,
                              hipStream_t stream) {
    const float* seq  = (const float*)d_in[0];
    const int*   head = (const int*)d_in[1];
    const int*   em   = (const int*)d_in[2];
    float* out = (float*)d_out;

    fused_kernel<<<B * M, 2 * Q4, 0, stream>>>(seq, head, em, out);
}